// Round 5
// baseline (221.617 us; speedup 1.0000x reference)
//
#include <hip/hip_runtime.h>

#define BN_EPS 1e-5f

typedef unsigned short u16;
typedef __bf16 bf16x8 __attribute__((ext_vector_type(8)));
typedef float floatx4 __attribute__((ext_vector_type(4)));
typedef u16 u16x4 __attribute__((ext_vector_type(4)));
typedef u16 u16x8 __attribute__((ext_vector_type(8)));

__device__ __forceinline__ u16 f2bf(float f) {
    union { float f; unsigned int u; } v; v.f = f;
    unsigned int r = (v.u + 0x7fffu + ((v.u >> 16) & 1u)) >> 16;
    return (u16)r;
}

// packed f32x2 -> bf16x2 (RNE), one VALU op
__device__ __forceinline__ unsigned int cvtpk(float lo, float hi) {
    unsigned int r;
    asm("v_cvt_pk_bf16_f32 %0, %1, %2" : "=v"(r) : "v"(lo), "v"(hi));
    return r;
}

// async 16B global->LDS; lane i lands at (wave-uniform) dst + i*16.
__device__ __forceinline__ void gld16(const void* gsrc, void* ldst) {
    __builtin_amdgcn_global_load_lds(
        (const __attribute__((address_space(1))) unsigned int*)gsrc,
        (__attribute__((address_space(3))) unsigned int*)ldst, 16, 0, 0);
}

// additive seg swizzle for transpose-staged [row][64] u16 tiles
__device__ __forceinline__ int addsw(int seg, int s) {
    return (seg + (s & 7) + ((s >> 3) & 7)) & 7;
}

// ---------------------------------------------------------------- prep ----
__global__ __launch_bounds__(256) void prep_kernel(
    const float* __restrict__ wt, const float* __restrict__ wp,
    const float* __restrict__ wg, const float* __restrict__ wz,
    const float* __restrict__ g1, const float* __restrict__ b1,
    const float* __restrict__ m1, const float* __restrict__ v1,
    const float* __restrict__ g2, const float* __restrict__ b2,
    const float* __restrict__ m2, const float* __restrict__ v2,
    const float* __restrict__ g3, const float* __restrict__ b3,
    const float* __restrict__ m3, const float* __restrict__ v3,
    const float* __restrict__ g4, const float* __restrict__ b4,
    const float* __restrict__ m4, const float* __restrict__ v4,
    u16* __restrict__ W1bf, float* __restrict__ shift1,
    u16* __restrict__ Wzbf, float* __restrict__ shift4)
{
    int id = blockIdx.x * 256 + threadIdx.x;
    if (id < 384 * 256) {
        int r = id >> 8, c = id & 255;
        int grp = r >> 7, ch = r & 127;
        const float* wsrc = grp == 0 ? wt : (grp == 1 ? wp : wg);
        const float* gg = grp == 0 ? g1 : (grp == 1 ? g2 : g3);
        const float* bb = grp == 0 ? b1 : (grp == 1 ? b2 : b3);
        const float* mm = grp == 0 ? m1 : (grp == 1 ? m2 : m3);
        const float* vv = grp == 0 ? v1 : (grp == 1 ? v2 : v3);
        float scale = gg[ch] * rsqrtf(vv[ch] + BN_EPS);
        W1bf[id] = f2bf(wsrc[ch * 256 + c] * scale);
        if (c == 0) shift1[r] = bb[ch] - mm[ch] * scale;
    }
    if (id < 256 * 128) {
        int o = id >> 7;
        float scale = g4[o] * rsqrtf(v4[o] + BN_EPS);
        Wzbf[id] = f2bf(wz[id] * scale);
        if ((id & 127) == 0) shift4[o] = b4[o] - m4[o] * scale;
    }
}

// ------------------------------------------------------------ K1 = g1+g2 --
// Block owns a 256-pixel window (2 subtiles of 128).  Per subtile: compute
// theta/phi/g (theta -> HBM; phi/g -> LDS), then KV[d][c] += g.phi^T MFMAs
// accumulate in regs across subtiles.  pg round-trip eliminated.
__global__ __launch_bounds__(512, 2) void k1_kernel(
    const float* __restrict__ x, const u16* __restrict__ W1,
    const float* __restrict__ shift1,
    u16* __restrict__ theta_sm, float* __restrict__ partials)
{
    const int sk = blockIdx.x, n = blockIdx.y;
    const int tid = threadIdx.x;
    const int w = tid >> 6, lane = tid & 63;
    const int quad = lane >> 4, l16 = lane & 15;

    __shared__ __align__(16) u16 ldsA[384 * 64];      // 48 KB W1 chunk
    __shared__ __align__(16) u16 ldsB[128 * 64];      // 16 KB x^T chunk
    __shared__ __align__(16) u16 ldsPG[4][128 * 64];  // 64 KB phiL,phiH,gL,gH

    floatx4 kv[8];
#pragma unroll
    for (int i = 0; i < 8; ++i) kv[i] = floatx4{0.f, 0.f, 0.f, 0.f};

    const int cp = w * 4 + quad;   // channel pair 0..31
    unsigned int* ldsBdw = (unsigned int*)ldsB;

    float4 xva[2][2], xvb[2][2];

    for (int ss = 0; ss < 2; ++ss) {
        const float* xb = x + ((size_t)n * 256 + 2 * cp) * 4096 + sk * 256 + ss * 128;

        floatx4 acc[3][8];
#pragma unroll
        for (int i = 0; i < 3; ++i)
#pragma unroll
            for (int j = 0; j < 8; ++j) acc[i][j] = floatx4{0.f, 0.f, 0.f, 0.f};

        auto loadx = [&](float4 (&xv)[2][2], int kc) {
#pragma unroll
            for (int ch = 0; ch < 2; ++ch)
#pragma unroll
                for (int hb = 0; hb < 2; ++hb)
                    xv[ch][hb] = *((const float4*)(xb + (size_t)(kc * 64 + ch) * 4096) + hb * 16 + l16);
        };
        auto writeB = [&](const float4 (&xv)[2][2]) {
#pragma unroll
            for (int hb = 0; hb < 2; ++hb)
#pragma unroll
                for (int j = 0; j < 4; ++j) {
                    int s = hb * 64 + l16 * 4 + j;
                    ldsBdw[s * 32 + addsw(w, s) * 4 + quad] =
                        cvtpk(((const float*)&xv[0][hb])[j], ((const float*)&xv[1][hb])[j]);
                }
        };
        auto stageA = [&](int kc) {
#pragma unroll
            for (int i = 0; i < 6; ++i) {
                int op = w * 6 + i;
                int r = op * 8 + (lane >> 3);
                int lseg = (lane & 7) ^ (r & 7);
                gld16(W1 + (size_t)r * 256 + kc * 64 + lseg * 8, ldsA + op * 512);
            }
        };

        loadx(xva, 0);
        for (int kc = 0; kc < 4; ++kc) {
            writeB((kc & 1) ? xvb : xva);
            stageA(kc);
            if (kc < 3) loadx((kc & 1) ? xva : xvb, kc + 1);
            __syncthreads();
#pragma unroll
            for (int kk = 0; kk < 2; ++kk) {
                bf16x8 a[3];
#pragma unroll
                for (int mt = 0; mt < 3; ++mt) {
                    int r = mt * 128 + w * 16 + l16;
                    int phys = (kk * 4 + quad) ^ (r & 7);
                    a[mt] = *(const bf16x8*)(ldsA + r * 64 + phys * 8);
                }
#pragma unroll
                for (int ni = 0; ni < 8; ++ni) {
                    int s = ni * 16 + l16;
                    int phys = addsw(kk * 4 + quad, s);
                    bf16x8 b = *(const bf16x8*)(ldsB + s * 64 + phys * 8);
#pragma unroll
                    for (int mt = 0; mt < 3; ++mt)
                        acc[mt][ni] = __builtin_amdgcn_mfma_f32_16x16x32_bf16(
                            a[mt], b, acc[mt][ni], 0, 0, 0);
                }
            }
            __syncthreads();
        }

        const int ocq = w * 16 + quad * 4;
        // theta -> HBM (s-major [s][c], 8B stores)
        {
            float sh0 = shift1[ocq + 0], sh1 = shift1[ocq + 1];
            float sh2 = shift1[ocq + 2], sh3 = shift1[ocq + 3];
#pragma unroll
            for (int ni = 0; ni < 8; ++ni) {
                int s = sk * 256 + ss * 128 + ni * 16 + l16;
                float v0 = acc[0][ni][0] + sh0, v1 = acc[0][ni][1] + sh1;
                float v2 = acc[0][ni][2] + sh2, v3 = acc[0][ni][3] + sh3;
                v0 = v0 > 0.f ? v0 : 0.f;
                v1 = v1 > 0.f ? v1 : 0.f;
                v2 = v2 > 0.f ? v2 : 0.f;
                v3 = v3 > 0.f ? v3 : 0.f;
                uint2 pk;
                pk.x = cvtpk(v0, v1);
                pk.y = cvtpk(v2, v3);
                *(uint2*)(theta_sm + (size_t)n * 524288 + (size_t)s * 128 + ocq) = pk;
            }
        }
        // phi (mt=1) -> ldsPG[0/1], g (mt=2) -> ldsPG[2/3]; rows [ch][64],
        // xor seg swizzle (phys = lseg ^ (ch&7)) matching the A-read pattern.
#pragma unroll
        for (int mt = 1; mt < 3; ++mt)
#pragma unroll
            for (int r = 0; r < 4; ++r) {
                int ch = ocq + r;
                float sh = shift1[mt * 128 + ch];
#pragma unroll
                for (int ni = 0; ni < 8; ++ni) {
                    int sl = ni * 16 + l16;
                    int half = sl >> 6, s6 = sl & 63;
                    int phys = (s6 >> 3) ^ (ch & 7);
                    float val = acc[mt][ni][r] + sh;
                    val = val > 0.f ? val : 0.f;
                    ldsPG[(mt - 1) * 2 + half][ch * 64 + phys * 8 + (s6 & 7)] = f2bf(val);
                }
            }
        __syncthreads();

        // KV[d][c] += sum_s g[d,s] * phi[c,s]; wave owns d rows w*16..+16
#pragma unroll
        for (int h = 0; h < 2; ++h)
#pragma unroll
            for (int kk = 0; kk < 2; ++kk) {
                int rd = w * 16 + l16;
                int physa = (kk * 4 + quad) ^ (rd & 7);
                bf16x8 a = *(const bf16x8*)(ldsPG[2 + h] + rd * 64 + physa * 8);
#pragma unroll
                for (int ci = 0; ci < 8; ++ci) {
                    int rc = ci * 16 + l16;
                    int physb = (kk * 4 + quad) ^ (rc & 7);
                    bf16x8 b = *(const bf16x8*)(ldsPG[h] + rc * 64 + physb * 8);
                    kv[ci] = __builtin_amdgcn_mfma_f32_16x16x32_bf16(a, b, kv[ci], 0, 0, 0);
                }
            }
        __syncthreads();
    }

    // partials[n][sk][d][c]
    float* outp = partials + (size_t)(n * 16 + sk) * 16384;
#pragma unroll
    for (int r = 0; r < 4; ++r) {
        int d = w * 16 + quad * 4 + r;
#pragma unroll
        for (int ci = 0; ci < 8; ++ci)
            outp[d * 128 + ci * 16 + l16] = kv[ci][r];
    }
}

// ----------------------------------------------------------- kv reduce ----
__global__ __launch_bounds__(256) void kv_reduce_kernel(
    const float* __restrict__ partials, u16* __restrict__ kvT)
{
    int n = blockIdx.y;
    int f4 = blockIdx.x * 256 + threadIdx.x;    // 0..4095
    const float4* p4 = (const float4*)partials;
    float4 s = {0.f, 0.f, 0.f, 0.f};
#pragma unroll
    for (int kc = 0; kc < 16; ++kc) {
        float4 v = p4[(size_t)(n * 16 + kc) * 4096 + f4];
        s.x += v.x; s.y += v.y; s.z += v.z; s.w += v.w;
    }
    u16x4 o; o[0] = f2bf(s.x); o[1] = f2bf(s.y); o[2] = f2bf(s.z); o[3] = f2bf(s.w);
    *(u16x4*)(kvT + (size_t)n * 16384 + f4 * 4) = o;
}

// ------------------------------------------------------------ K34 = g3+g4 -
// Reference does reshape [n,S,C'] -> [n,C',h,w] (NOT transpose), so
// y[c2][s2 = st*128+j] = out_sd_flat[c2*4096 + st*128 + j]
//                      = (theta @ kvT^T)[s = c2*32 + st][d = j].
// Block (st,n): phase 1 computes y_loc[c2][j] from the stride-32 comb of
// theta rows s = c2*32 + st (offset c2*4096 + st*128 u16); writes it
// TRANSPOSED into LDS as [j][c2].  Phase 2: out[o][st*128+j] =
// relu(sum_c2 Wz[o][c2]*y_loc[c2][j] + shift4[o] + x).  No HBM round-trip.
__global__ __launch_bounds__(512, 2) void k34_kernel(
    const u16* __restrict__ theta_sm, const u16* __restrict__ kvT,
    const u16* __restrict__ Wz, const float* __restrict__ shift4,
    const float* __restrict__ x, float* __restrict__ out)
{
    const int st = blockIdx.x, n = blockIdx.y;   // st 0..31
    const int tid = threadIdx.x;
    const int w = tid >> 6, lane = tid & 63;
    const int quad = lane >> 4, l16 = lane & 15;

    // 96 KB pool: phase1 dbuf T/K tiles (64 KB, reused by Wz in phase 2)
    // + y tile (32 KB).
    __shared__ __align__(16) u16 lds[49152];
    u16* T0 = lds;            // theta chunk buf0  (8K u16)
    u16* K0 = lds + 8192;     // kvT  chunk buf0
    u16* T1 = lds + 16384;    // buf1
    u16* K1 = lds + 24576;
    u16* Y  = lds + 32768;    // y^T [2 c2-halves][128 j][64]  (16K u16)

    // row c2 lives at theta + (c2*32 + st)*128 = tbase + c2*4096
    const u16* tbase = theta_sm + (size_t)n * 524288 + (size_t)st * 128;
    const u16* kbase = kvT + (size_t)n * 16384;

    floatx4 acc3[8];
#pragma unroll
    for (int i = 0; i < 8; ++i) acc3[i] = floatx4{0.f, 0.f, 0.f, 0.f};

    auto stageTK = [&](u16* T, u16* K, int ch) {
#pragma unroll
        for (int i = 0; i < 2; ++i) {
            int op = w * 2 + i;
            int r = op * 8 + (lane >> 3);       // = c2 for T, = d for K
            int lseg = (lane & 7) ^ (r & 7);
            gld16(tbase + (size_t)r * 4096 + ch * 64 + lseg * 8, T + op * 512);
            gld16(kbase + (size_t)r * 128 + ch * 64 + lseg * 8, K + op * 512);
        }
    };
    auto comp3 = [&](const u16* T, const u16* K) {
#pragma unroll
        for (int kk = 0; kk < 2; ++kk) {
            int rc2 = w * 16 + l16;             // c2 tile row
            int physa = (kk * 4 + quad) ^ (rc2 & 7);
            bf16x8 a = *(const bf16x8*)(T + rc2 * 64 + physa * 8);
#pragma unroll
            for (int di = 0; di < 8; ++di) {
                int rd = di * 16 + l16;         // d = j
                int physb = (kk * 4 + quad) ^ (rd & 7);
                bf16x8 b = *(const bf16x8*)(K + rd * 64 + physb * 8);
                acc3[di] = __builtin_amdgcn_mfma_f32_16x16x32_bf16(a, b, acc3[di], 0, 0, 0);
            }
        }
    };

    stageTK(T0, K0, 0);
    __syncthreads();
    stageTK(T1, K1, 1);
    comp3(T0, K0);
    __syncthreads();
    comp3(T1, K1);

    // acc3[di][r] = y_loc[c2 = w*16 + quad*4 + r][j = di*16 + l16].
    // Write TRANSPOSED: Y[half c2][row j][col c64], phys = (c64>>3)^(j&7).
#pragma unroll
    for (int di = 0; di < 8; ++di) {
        int j = di * 16 + l16;
#pragma unroll
        for (int r = 0; r < 4; ++r) {
            int c2 = w * 16 + quad * 4 + r;
            int half = c2 >> 6, c64 = c2 & 63;
            int phys = (c64 >> 3) ^ (j & 7);
            Y[half * 8192 + j * 64 + phys * 8 + (c64 & 7)] = f2bf(acc3[di][r]);
        }
    }
    // stage Wz chunk 0 (all 256 o rows, c2 0..63) into T0K0 region
#pragma unroll
    for (int i = 0; i < 4; ++i) {
        int op = w * 4 + i;
        int r = op * 8 + (lane >> 3);
        int lseg = (lane & 7) ^ (r & 7);
        gld16(Wz + (size_t)r * 128 + 0 * 64 + lseg * 8, lds + op * 512);
    }
    __syncthreads();

    floatx4 acc4[2][8];
#pragma unroll
    for (int i = 0; i < 2; ++i)
#pragma unroll
        for (int j = 0; j < 8; ++j) acc4[i][j] = floatx4{0.f, 0.f, 0.f, 0.f};

    auto comp4 = [&](const u16* WL, int ch) {
#pragma unroll
        for (int kk = 0; kk < 2; ++kk) {
            bf16x8 a[2];
#pragma unroll
            for (int mi = 0; mi < 2; ++mi) {
                int r = w * 32 + mi * 16 + l16;
                int phys = (kk * 4 + quad) ^ (r & 7);
                a[mi] = *(const bf16x8*)(WL + r * 64 + phys * 8);
            }
#pragma unroll
            for (int ni = 0; ni < 8; ++ni) {
                int s = ni * 16 + l16;          // j
                int phys = (kk * 4 + quad) ^ (s & 7);
                bf16x8 b = *(const bf16x8*)(Y + ch * 8192 + s * 64 + phys * 8);
#pragma unroll
                for (int mi = 0; mi < 2; ++mi)
                    acc4[mi][ni] = __builtin_amdgcn_mfma_f32_16x16x32_bf16(
                        a[mi], b, acc4[mi][ni], 0, 0, 0);
            }
        }
    };

    // stage Wz chunk 1 into T1K1 region, then compute chunk 0
#pragma unroll
    for (int i = 0; i < 4; ++i) {
        int op = w * 4 + i;
        int r = op * 8 + (lane >> 3);
        int lseg = (lane & 7) ^ (r & 7);
        gld16(Wz + (size_t)r * 128 + 1 * 64 + lseg * 8, lds + 16384 + op * 512);
    }
    comp4(lds, 0);
    __syncthreads();
    comp4(lds + 16384, 1);

#pragma unroll
    for (int mi = 0; mi < 2; ++mi)
#pragma unroll
        for (int r = 0; r < 4; ++r) {
            int o = w * 32 + mi * 16 + quad * 4 + r;
            float sh = shift4[o];
#pragma unroll
            for (int ni = 0; ni < 8; ++ni) {
                int s2 = st * 128 + ni * 16 + l16;
                size_t idx = ((size_t)n * 256 + o) * 4096 + s2;
                float val = acc4[mi][ni][r] + sh + x[idx];
                out[idx] = val > 0.f ? val : 0.f;
            }
        }
}

// -------------------------------------------------------------- launch ----
extern "C" void kernel_launch(void* const* d_in, const int* in_sizes, int n_in,
                              void* d_out, int out_size, void* d_ws, size_t ws_size,
                              hipStream_t stream)
{
    const float* x  = (const float*)d_in[0];
    const float* wt = (const float*)d_in[1];
    const float* wp = (const float*)d_in[2];
    const float* wg = (const float*)d_in[3];
    const float* wz = (const float*)d_in[4];
    const float* bn[16];
    for (int i = 0; i < 16; ++i) bn[i] = (const float*)d_in[5 + i];

    char* ws = (char*)d_ws;
    u16*   W1bf     = (u16*)  (ws + 0);          // 196608
    float* shift1   = (float*)(ws + 196608);     // 1536
    u16*   Wzbf     = (u16*)  (ws + 198144);     // 65536
    float* shift4   = (float*)(ws + 263680);     // 1024
    u16*   theta_sm = (u16*)  (ws + 264704);     // 16*4096*128*2 = 16777216
    float* partials = (float*)(ws + 17041920);   // 16*16*16384*4 = 16777216
    u16*   kvT      = (u16*)  (ws + 33819136);   // 524288
    float* out = (float*)d_out;

    prep_kernel<<<384, 256, 0, stream>>>(
        wt, wp, wg, wz,
        bn[0], bn[1], bn[2], bn[3],
        bn[4], bn[5], bn[6], bn[7],
        bn[8], bn[9], bn[10], bn[11],
        bn[12], bn[13], bn[14], bn[15],
        W1bf, shift1, Wzbf, shift4);

    k1_kernel<<<dim3(16, 16), 512, 0, stream>>>(x, W1bf, shift1, theta_sm, partials);
    kv_reduce_kernel<<<dim3(16, 16), 256, 0, stream>>>(partials, kvT);
    k34_kernel<<<dim3(32, 16), 512, 0, stream>>>(theta_sm, kvT, Wzbf, shift4, x, out);
}